// Round 1
// baseline (1031.934 us; speedup 1.0000x reference)
//
#include <hip/hip_runtime.h>
#include <hip/hip_bf16.h>

#define B_N    8192
#define Z_N    10
#define IN_D   512
#define OUT_D  512
#define R_N    8
#define M_N    3
#define SCALING 1.0f
#define ALPHA   0.04419417382415922f   // 1/sqrt(512)

__device__ __forceinline__ float bfbits_lo(unsigned int u) {
    return __uint_as_float(u << 16);
}
__device__ __forceinline__ float bfbits_hi(unsigned int u) {
    return __uint_as_float(u & 0xffff0000u);
}

// round-to-nearest-even f32 -> bf16 bits
__device__ __forceinline__ unsigned short f2bf(float f) {
    unsigned int x = __float_as_uint(f);
    x += 0x7fffu + ((x >> 16) & 1u);
    return (unsigned short)(x >> 16);
}

// Kernel 1: merged W[z,o,i] = (weights + A^T (B*scaling)) * alpha, stored bf16.
// grid = Z_N*OUT_D blocks of 256 threads; block = (z,o) pair.
__global__ __launch_bounds__(256) void merge_w_kernel(
    const float* __restrict__ weights, const float* __restrict__ lora_A,
    const float* __restrict__ lora_B, unsigned short* __restrict__ Wbf) {
    int zo = blockIdx.x;
    int z = zo >> 9;          // / OUT_D
    int o = zo & (OUT_D - 1);
    int tid = threadIdx.x;

    float lb[R_N];
    const float* bp = lora_B + ((size_t)z * OUT_D + o) * R_N;
#pragma unroll
    for (int r = 0; r < R_N; ++r) lb[r] = bp[r] * SCALING;

    const float* ap = lora_A + (size_t)z * R_N * IN_D;
    const float* wp = weights + ((size_t)z * OUT_D + o) * IN_D;
    unsigned short* op = Wbf + ((size_t)z * OUT_D + o) * IN_D;

    for (int i = tid; i < IN_D; i += 256) {
        float acc = wp[i];
#pragma unroll
        for (int r = 0; r < R_N; ++r) acc += ap[r * IN_D + i] * lb[r];
        acc *= ALPHA;
        op[i] = f2bf(acc);
    }
}

// Kernel 2: one block per node. t[b] staged in LDS (broadcast reads),
// each thread owns 2 output rows, streams bf16 W rows as uint4.
__global__ __launch_bounds__(256) void apply_kernel(
    const float* __restrict__ t, const float* __restrict__ attrs,
    const unsigned short* __restrict__ Wbf, float* __restrict__ out) {
    int b = blockIdx.x;
    int tid = threadIdx.x;

    // z_b from one-hot
    const float* ab = attrs + (size_t)b * Z_N;
    int z = 0;
#pragma unroll
    for (int zz = 1; zz < Z_N; ++zz)
        if (ab[zz] > 0.5f) z = zz;

    __shared__ __align__(16) float t_s[IN_D * M_N];
    const float* tb = t + (size_t)b * (IN_D * M_N);
    for (int k = tid; k < IN_D * M_N; k += 256) t_s[k] = tb[k];
    __syncthreads();

    const unsigned short* w0 = Wbf + ((size_t)z * OUT_D + tid) * IN_D;
    const unsigned short* w1 = w0 + 256 * IN_D;

    float acc0[M_N] = {0.f, 0.f, 0.f};
    float acc1[M_N] = {0.f, 0.f, 0.f};

    for (int c = 0; c < IN_D; c += 8) {
        uint4 u0 = *reinterpret_cast<const uint4*>(w0 + c);
        uint4 u1 = *reinterpret_cast<const uint4*>(w1 + c);

        float wf0[8], wf1[8];
        {
            unsigned int a0[4] = {u0.x, u0.y, u0.z, u0.w};
            unsigned int a1[4] = {u1.x, u1.y, u1.z, u1.w};
#pragma unroll
            for (int q = 0; q < 4; ++q) {
                wf0[2 * q]     = bfbits_lo(a0[q]);
                wf0[2 * q + 1] = bfbits_hi(a0[q]);
                wf1[2 * q]     = bfbits_lo(a1[q]);
                wf1[2 * q + 1] = bfbits_hi(a1[q]);
            }
        }

        float tf[24];
        const float4* tv = reinterpret_cast<const float4*>(t_s + c * M_N);
#pragma unroll
        for (int q = 0; q < 6; ++q) {
            float4 v = tv[q];
            tf[4 * q + 0] = v.x; tf[4 * q + 1] = v.y;
            tf[4 * q + 2] = v.z; tf[4 * q + 3] = v.w;
        }

#pragma unroll
        for (int cc = 0; cc < 8; ++cc) {
#pragma unroll
            for (int d = 0; d < M_N; ++d) {
                acc0[d] += wf0[cc] * tf[cc * M_N + d];
                acc1[d] += wf1[cc] * tf[cc * M_N + d];
            }
        }
    }

    float* ob = out + (size_t)b * (OUT_D * M_N);
#pragma unroll
    for (int d = 0; d < M_N; ++d) ob[tid * M_N + d] = acc0[d];
#pragma unroll
    for (int d = 0; d < M_N; ++d) ob[(tid + 256) * M_N + d] = acc1[d];
}

// Fallback if ws is too small: merge W on the fly (A[z] staged in LDS).
__global__ __launch_bounds__(256) void apply_fallback_kernel(
    const float* __restrict__ t, const float* __restrict__ attrs,
    const float* __restrict__ weights, const float* __restrict__ lora_A,
    const float* __restrict__ lora_B, float* __restrict__ out) {
    int b = blockIdx.x;
    int tid = threadIdx.x;

    const float* ab = attrs + (size_t)b * Z_N;
    int z = 0;
#pragma unroll
    for (int zz = 1; zz < Z_N; ++zz)
        if (ab[zz] > 0.5f) z = zz;

    __shared__ __align__(16) float t_s[IN_D * M_N];
    __shared__ __align__(16) float a_s[R_N * IN_D];
    const float* tb = t + (size_t)b * (IN_D * M_N);
    for (int k = tid; k < IN_D * M_N; k += 256) t_s[k] = tb[k];
    const float* ap = lora_A + (size_t)z * R_N * IN_D;
    for (int k = tid; k < R_N * IN_D; k += 256) a_s[k] = ap[k];
    __syncthreads();

    int C0 = tid, C1 = tid + 256;
    float lb0[R_N], lb1[R_N];
    const float* bp = lora_B + (size_t)z * OUT_D * R_N;
#pragma unroll
    for (int r = 0; r < R_N; ++r) {
        lb0[r] = bp[C0 * R_N + r] * (SCALING * ALPHA);
        lb1[r] = bp[C1 * R_N + r] * (SCALING * ALPHA);
    }
    const float* wr0 = weights + ((size_t)z * OUT_D + C0) * IN_D;
    const float* wr1 = weights + ((size_t)z * OUT_D + C1) * IN_D;

    float acc0[M_N] = {0.f, 0.f, 0.f};
    float acc1[M_N] = {0.f, 0.f, 0.f};

    for (int c = 0; c < IN_D; c += 4) {
        float4 wv0 = *reinterpret_cast<const float4*>(wr0 + c);
        float4 wv1 = *reinterpret_cast<const float4*>(wr1 + c);
        float w0a[4] = {wv0.x, wv0.y, wv0.z, wv0.w};
        float w1a[4] = {wv1.x, wv1.y, wv1.z, wv1.w};
#pragma unroll
        for (int cc = 0; cc < 4; ++cc) {
            float wa = w0a[cc] * ALPHA;
            float wb = w1a[cc] * ALPHA;
#pragma unroll
            for (int r = 0; r < R_N; ++r) {
                float av = a_s[r * IN_D + c + cc];
                wa += av * lb0[r];
                wb += av * lb1[r];
            }
#pragma unroll
            for (int d = 0; d < M_N; ++d) {
                float tv = t_s[(c + cc) * M_N + d];
                acc0[d] += wa * tv;
                acc1[d] += wb * tv;
            }
        }
    }

    float* ob = out + (size_t)b * (OUT_D * M_N);
#pragma unroll
    for (int d = 0; d < M_N; ++d) { ob[C0 * M_N + d] = acc0[d]; ob[C1 * M_N + d] = acc1[d]; }
}

extern "C" void kernel_launch(void* const* d_in, const int* in_sizes, int n_in,
                              void* d_out, int out_size, void* d_ws, size_t ws_size,
                              hipStream_t stream) {
    const float* t       = (const float*)d_in[0];
    const float* attrs   = (const float*)d_in[1];
    const float* weights = (const float*)d_in[2];
    const float* lora_A  = (const float*)d_in[3];
    const float* lora_B  = (const float*)d_in[4];
    float* out = (float*)d_out;

    size_t needed = (size_t)Z_N * OUT_D * IN_D * sizeof(unsigned short);
    if (ws_size >= needed) {
        unsigned short* Wbf = (unsigned short*)d_ws;
        merge_w_kernel<<<Z_N * OUT_D, 256, 0, stream>>>(weights, lora_A, lora_B, Wbf);
        apply_kernel<<<B_N, 256, 0, stream>>>(t, attrs, Wbf, out);
    } else {
        apply_fallback_kernel<<<B_N, 256, 0, stream>>>(t, attrs, weights, lora_A, lora_B, out);
    }
}

// Round 2
// 124.684 us; speedup vs baseline: 8.2764x; 8.2764x over previous
//
#include <hip/hip_runtime.h>
#include <hip/hip_bf16.h>

#define B_N    8192
#define Z_N    10
#define IN_D   512
#define OUT_D  512
#define R_N    8
#define M_N    3
#define SCALING 1.0f
#define ALPHA   0.04419417382415922f   // 1/sqrt(512)

// ---- GEMM tiling ----
#define BM 128
#define BN 96            // 32 nodes * 3
#define BK 64
#define NPC 32           // nodes per chunk
#define MAXCHUNKS 266    // sum_z ceil(N_z/32) <= 256 + 9
#define LDS_STRIDE 144   // bytes per LDS row: 64 bf16 = 128B + 16B pad (kills super-floor conflicts)

// ---- ws layout (bytes) ----
#define OFF_WBF  0u
#define SZ_WBF   (Z_N * OUT_D * IN_D * 2u)                 // 5,242,880
#define OFF_TBF  (OFF_WBF + SZ_WBF)
#define SZ_TBF   (B_N * IN_D * M_N * 2u)                   // 25,165,824
#define OFF_PERM (OFF_TBF + SZ_TBF)
#define SZ_PERM  (B_N * 4u)
#define OFF_ZARR (OFF_PERM + SZ_PERM)
#define SZ_ZARR  (B_N * 4u)
#define OFF_META (OFF_ZARR + SZ_ZARR)
#define SZ_META  ((1u + 3u * MAXCHUNKS) * 4u)
#define WS_NEED_FULL (OFF_META + SZ_META)

typedef __attribute__((ext_vector_type(8))) short short8v;
typedef __attribute__((ext_vector_type(4))) float float4v;

__device__ __forceinline__ float bfbits_lo(unsigned int u) {
    return __uint_as_float(u << 16);
}
__device__ __forceinline__ float bfbits_hi(unsigned int u) {
    return __uint_as_float(u & 0xffff0000u);
}

// round-to-nearest-even f32 -> bf16 bits
__device__ __forceinline__ unsigned short f2bf(float f) {
    unsigned int x = __float_as_uint(f);
    x += 0x7fffu + ((x >> 16) & 1u);
    return (unsigned short)(x >> 16);
}

// ---------------------------------------------------------------------------
// Kernel 1: merged W[z,o,i] = (weights + A^T (B*scaling)) * alpha, stored bf16.
// ---------------------------------------------------------------------------
__global__ __launch_bounds__(256) void merge_w_kernel(
    const float* __restrict__ weights, const float* __restrict__ lora_A,
    const float* __restrict__ lora_B, unsigned short* __restrict__ Wbf) {
    int zo = blockIdx.x;
    int z = zo >> 9;          // / OUT_D
    int o = zo & (OUT_D - 1);
    int tid = threadIdx.x;

    float lb[R_N];
    const float* bp = lora_B + ((size_t)z * OUT_D + o) * R_N;
#pragma unroll
    for (int r = 0; r < R_N; ++r) lb[r] = bp[r] * SCALING;

    const float* ap = lora_A + (size_t)z * R_N * IN_D;
    const float* wp = weights + ((size_t)z * OUT_D + o) * IN_D;
    unsigned short* op = Wbf + ((size_t)z * OUT_D + o) * IN_D;

    for (int i = tid; i < IN_D; i += 256) {
        float acc = wp[i];
#pragma unroll
        for (int r = 0; r < R_N; ++r) acc += ap[r * IN_D + i] * lb[r];
        acc *= ALPHA;
        op[i] = f2bf(acc);
    }
}

// ---------------------------------------------------------------------------
// Kernel 2: t [n][k][d] fp32 -> tbf [n][d][k] bf16 (columns K-contiguous)
// ---------------------------------------------------------------------------
__global__ __launch_bounds__(256) void convert_t_kernel(
    const float* __restrict__ t, unsigned short* __restrict__ tbf) {
    unsigned stride = gridDim.x * 256u;
    const unsigned total = B_N * IN_D * M_N;
    for (unsigned idx = blockIdx.x * 256u + threadIdx.x; idx < total; idx += stride) {
        unsigned n = idx / (IN_D * M_N);
        unsigned rem = idx - n * (IN_D * M_N);
        unsigned d = rem >> 9;        // / IN_D
        unsigned k = rem & (IN_D - 1);
        tbf[idx] = f2bf(t[n * (IN_D * M_N) + k * M_N + d]);
    }
}

// ---------------------------------------------------------------------------
// Kernel 3: counting sort of nodes by z + chunk table (single block)
// meta: [0]=chunk_count; [1..]=chunk_z; [1+MAXCHUNKS..]=chunk_nstart;
//       [1+2*MAXCHUNKS..]=chunk_nn
// ---------------------------------------------------------------------------
__global__ __launch_bounds__(256) void sort_kernel(
    const float* __restrict__ attrs, int* __restrict__ perm,
    int* __restrict__ zarr, int* __restrict__ meta) {
    __shared__ int hist[Z_N];
    __shared__ int offs[Z_N];
    int tid = threadIdx.x;
    if (tid < Z_N) hist[tid] = 0;
    __syncthreads();
    for (int n = tid; n < B_N; n += 256) {
        const float* a = attrs + (size_t)n * Z_N;
        int z = 0;
#pragma unroll
        for (int zz = 1; zz < Z_N; ++zz)
            if (a[zz] > 0.5f) z = zz;
        zarr[n] = z;
        atomicAdd(&hist[z], 1);
    }
    __syncthreads();
    if (tid == 0) {
        int cum = 0, nc = 0;
        for (int z = 0; z < Z_N; ++z) {
            int c = hist[z];
            offs[z] = cum;
            for (int j = 0; j < c; j += NPC) {
                meta[1 + nc] = z;
                meta[1 + MAXCHUNKS + nc] = cum + j;
                meta[1 + 2 * MAXCHUNKS + nc] = (c - j < NPC) ? (c - j) : NPC;
                ++nc;
            }
            cum += c;
        }
        meta[0] = nc;
    }
    __syncthreads();
    for (int n = tid; n < B_N; n += 256) {
        int z = zarr[n];
        int pos = atomicAdd(&offs[z], 1);
        perm[pos] = n;
    }
}

// ---------------------------------------------------------------------------
// Kernel 4: grouped GEMM. One block = (chunk of <=32 same-z nodes) x (128-row
// strip of OUT). C[o, (n,d)] = sum_k W[z][o][k] * tbf[n][d][k].
// 4 waves, each 64x48 = 4x3 fragments of mfma_f32_16x16x32_bf16.
// ---------------------------------------------------------------------------
__global__ __launch_bounds__(256) void gemm_kernel(
    const unsigned short* __restrict__ Wbf,
    const unsigned short* __restrict__ tbf,
    const int* __restrict__ perm,
    const int* __restrict__ meta,
    float* __restrict__ out) {
    int chunk = blockIdx.x >> 2;
    if (chunk >= meta[0]) return;
    int row0 = (blockIdx.x & 3) * BM;
    int z  = meta[1 + chunk];
    int ns = meta[1 + MAXCHUNKS + chunk];
    int nn = meta[1 + 2 * MAXCHUNKS + chunk];

    __shared__ __align__(16) char A_s[BM * LDS_STRIDE];
    __shared__ __align__(16) char B_s[BN * LDS_STRIDE];
    __shared__ int col_tb[BN];   // tbf element base per local col, -1 invalid
    __shared__ int col_ob[BN];   // out element base per local col

    int tid = threadIdx.x;
    if (tid < BN) {
        int nl = tid / 3;
        int d  = tid - nl * 3;
        int bt = -1, bo = -1;
        if (nl < nn) {
            int node = perm[ns + nl];
            bt = node * (IN_D * M_N) + d * IN_D;
            bo = node * (OUT_D * M_N) + d;
        }
        col_tb[tid] = bt;
        col_ob[tid] = bo;
    }

    const unsigned short* Wz = Wbf + (size_t)z * OUT_D * IN_D + (size_t)row0 * IN_D;

    int lane = tid & 63;
    int wid  = tid >> 6;
    int wrow = (wid & 1) * 64;
    int wcol = (wid >> 1) * 48;
    int lrow = lane & 15;
    int g    = lane >> 4;

    float4v acc[4][3];
#pragma unroll
    for (int mi = 0; mi < 4; ++mi)
#pragma unroll
        for (int ni = 0; ni < 3; ++ni) acc[mi][ni] = (float4v){0.f, 0.f, 0.f, 0.f};

    for (int kt = 0; kt < IN_D / BK; ++kt) {
        __syncthreads();   // also covers col_tb/col_ob availability at kt=0
        // stage A: 128 rows x 8 units of 16B; consecutive tids -> contiguous 16B
#pragma unroll
        for (int j = 0; j < 4; ++j) {
            int id = tid + 256 * j;
            int row = id >> 3, u = id & 7;
            short8v v = *reinterpret_cast<const short8v*>(Wz + (size_t)row * IN_D + kt * BK + u * 8);
            *reinterpret_cast<short8v*>(A_s + row * LDS_STRIDE + u * 16) = v;
        }
        // stage B: 96 cols x 8 units of 16B (gathered via col_tb)
#pragma unroll
        for (int j = 0; j < 3; ++j) {
            int id = tid + 256 * j;
            int lc = id >> 3, u = id & 7;
            int bt = col_tb[lc];
            short8v v;
            if (bt >= 0)
                v = *reinterpret_cast<const short8v*>(tbf + bt + kt * BK + u * 8);
            else
                v = (short8v){0, 0, 0, 0, 0, 0, 0, 0};
            *reinterpret_cast<short8v*>(B_s + lc * LDS_STRIDE + u * 16) = v;
        }
        __syncthreads();
#pragma unroll
        for (int kk = 0; kk < 2; ++kk) {
            short8v a[4], b[3];
#pragma unroll
            for (int mi = 0; mi < 4; ++mi) {
                int row = wrow + mi * 16 + lrow;
                a[mi] = *reinterpret_cast<const short8v*>(A_s + row * LDS_STRIDE + kk * 64 + g * 16);
            }
#pragma unroll
            for (int ni = 0; ni < 3; ++ni) {
                int col = wcol + ni * 16 + lrow;
                b[ni] = *reinterpret_cast<const short8v*>(B_s + col * LDS_STRIDE + kk * 64 + g * 16);
            }
#pragma unroll
            for (int mi = 0; mi < 4; ++mi)
#pragma unroll
                for (int ni = 0; ni < 3; ++ni)
                    acc[mi][ni] = __builtin_amdgcn_mfma_f32_16x16x32_bf16(
                        a[mi], b[ni], acc[mi][ni], 0, 0, 0);
        }
    }

    // C store: C/D layout col=lane&15, row=(lane>>4)*4+e (m89-verified)
    int ncols = nn * M_N;
#pragma unroll
    for (int ni = 0; ni < 3; ++ni) {
        int lc = wcol + ni * 16 + lrow;
        if (lc >= ncols) continue;
        int ob = col_ob[lc];
#pragma unroll
        for (int mi = 0; mi < 4; ++mi) {
            int orow = row0 + wrow + mi * 16 + g * 4;
#pragma unroll
            for (int e = 0; e < 4; ++e)
                out[ob + (size_t)(orow + e) * M_N] = acc[mi][ni][e];
        }
    }
}

// ---------------------------------------------------------------------------
// Fallback kernels (round-1 path) if ws is too small
// ---------------------------------------------------------------------------
__global__ __launch_bounds__(256) void apply_kernel(
    const float* __restrict__ t, const float* __restrict__ attrs,
    const unsigned short* __restrict__ Wbf, float* __restrict__ out) {
    int b = blockIdx.x;
    int tid = threadIdx.x;

    const float* ab = attrs + (size_t)b * Z_N;
    int z = 0;
#pragma unroll
    for (int zz = 1; zz < Z_N; ++zz)
        if (ab[zz] > 0.5f) z = zz;

    __shared__ __align__(16) float t_s[IN_D * M_N];
    const float* tb = t + (size_t)b * (IN_D * M_N);
    for (int k = tid; k < IN_D * M_N; k += 256) t_s[k] = tb[k];
    __syncthreads();

    const unsigned short* w0 = Wbf + ((size_t)z * OUT_D + tid) * IN_D;
    const unsigned short* w1 = w0 + 256 * IN_D;

    float acc0[M_N] = {0.f, 0.f, 0.f};
    float acc1[M_N] = {0.f, 0.f, 0.f};

    for (int c = 0; c < IN_D; c += 8) {
        uint4 u0 = *reinterpret_cast<const uint4*>(w0 + c);
        uint4 u1 = *reinterpret_cast<const uint4*>(w1 + c);

        float wf0[8], wf1[8];
        {
            unsigned int a0[4] = {u0.x, u0.y, u0.z, u0.w};
            unsigned int a1[4] = {u1.x, u1.y, u1.z, u1.w};
#pragma unroll
            for (int q = 0; q < 4; ++q) {
                wf0[2 * q]     = bfbits_lo(a0[q]);
                wf0[2 * q + 1] = bfbits_hi(a0[q]);
                wf1[2 * q]     = bfbits_lo(a1[q]);
                wf1[2 * q + 1] = bfbits_hi(a1[q]);
            }
        }

        float tf[24];
        const float4* tv = reinterpret_cast<const float4*>(t_s + c * M_N);
#pragma unroll
        for (int q = 0; q < 6; ++q) {
            float4 v = tv[q];
            tf[4 * q + 0] = v.x; tf[4 * q + 1] = v.y;
            tf[4 * q + 2] = v.z; tf[4 * q + 3] = v.w;
        }

#pragma unroll
        for (int cc = 0; cc < 8; ++cc) {
#pragma unroll
            for (int d = 0; d < M_N; ++d) {
                acc0[d] += wf0[cc] * tf[cc * M_N + d];
                acc1[d] += wf1[cc] * tf[cc * M_N + d];
            }
        }
    }

    float* ob = out + (size_t)b * (OUT_D * M_N);
#pragma unroll
    for (int d = 0; d < M_N; ++d) ob[tid * M_N + d] = acc0[d];
#pragma unroll
    for (int d = 0; d < M_N; ++d) ob[(tid + 256) * M_N + d] = acc1[d];
}

__global__ __launch_bounds__(256) void apply_fallback_kernel(
    const float* __restrict__ t, const float* __restrict__ attrs,
    const float* __restrict__ weights, const float* __restrict__ lora_A,
    const float* __restrict__ lora_B, float* __restrict__ out) {
    int b = blockIdx.x;
    int tid = threadIdx.x;

    const float* ab = attrs + (size_t)b * Z_N;
    int z = 0;
#pragma unroll
    for (int zz = 1; zz < Z_N; ++zz)
        if (ab[zz] > 0.5f) z = zz;

    __shared__ __align__(16) float t_s[IN_D * M_N];
    __shared__ __align__(16) float a_s[R_N * IN_D];
    const float* tb = t + (size_t)b * (IN_D * M_N);
    for (int k = tid; k < IN_D * M_N; k += 256) t_s[k] = tb[k];
    const float* ap = lora_A + (size_t)z * R_N * IN_D;
    for (int k = tid; k < R_N * IN_D; k += 256) a_s[k] = ap[k];
    __syncthreads();

    int C0 = tid, C1 = tid + 256;
    float lb0[R_N], lb1[R_N];
    const float* bp = lora_B + (size_t)z * OUT_D * R_N;
#pragma unroll
    for (int r = 0; r < R_N; ++r) {
        lb0[r] = bp[C0 * R_N + r] * (SCALING * ALPHA);
        lb1[r] = bp[C1 * R_N + r] * (SCALING * ALPHA);
    }
    const float* wr0 = weights + ((size_t)z * OUT_D + C0) * IN_D;
    const float* wr1 = weights + ((size_t)z * OUT_D + C1) * IN_D;

    float acc0[M_N] = {0.f, 0.f, 0.f};
    float acc1[M_N] = {0.f, 0.f, 0.f};

    for (int c = 0; c < IN_D; c += 4) {
        float4 wv0 = *reinterpret_cast<const float4*>(wr0 + c);
        float4 wv1 = *reinterpret_cast<const float4*>(wr1 + c);
        float w0a[4] = {wv0.x, wv0.y, wv0.z, wv0.w};
        float w1a[4] = {wv1.x, wv1.y, wv1.z, wv1.w};
#pragma unroll
        for (int cc = 0; cc < 4; ++cc) {
            float wa = w0a[cc] * ALPHA;
            float wb = w1a[cc] * ALPHA;
#pragma unroll
            for (int r = 0; r < R_N; ++r) {
                float av = a_s[r * IN_D + c + cc];
                wa += av * lb0[r];
                wb += av * lb1[r];
            }
#pragma unroll
            for (int d = 0; d < M_N; ++d) {
                float tv = t_s[(c + cc) * M_N + d];
                acc0[d] += wa * tv;
                acc1[d] += wb * tv;
            }
        }
    }

    float* ob = out + (size_t)b * (OUT_D * M_N);
#pragma unroll
    for (int d = 0; d < M_N; ++d) { ob[C0 * M_N + d] = acc0[d]; ob[C1 * M_N + d] = acc1[d]; }
}

extern "C" void kernel_launch(void* const* d_in, const int* in_sizes, int n_in,
                              void* d_out, int out_size, void* d_ws, size_t ws_size,
                              hipStream_t stream) {
    const float* t       = (const float*)d_in[0];
    const float* attrs   = (const float*)d_in[1];
    const float* weights = (const float*)d_in[2];
    const float* lora_A  = (const float*)d_in[3];
    const float* lora_B  = (const float*)d_in[4];
    float* out = (float*)d_out;

    char* ws = (char*)d_ws;

    if (ws_size >= WS_NEED_FULL) {
        unsigned short* Wbf = (unsigned short*)(ws + OFF_WBF);
        unsigned short* tbf = (unsigned short*)(ws + OFF_TBF);
        int* perm = (int*)(ws + OFF_PERM);
        int* zarr = (int*)(ws + OFF_ZARR);
        int* meta = (int*)(ws + OFF_META);

        merge_w_kernel<<<Z_N * OUT_D, 256, 0, stream>>>(weights, lora_A, lora_B, Wbf);
        convert_t_kernel<<<4096, 256, 0, stream>>>(t, tbf);
        sort_kernel<<<1, 256, 0, stream>>>(attrs, perm, zarr, meta);
        gemm_kernel<<<MAXCHUNKS * 4, 256, 0, stream>>>(Wbf, tbf, perm, meta, out);
    } else if (ws_size >= SZ_WBF) {
        unsigned short* Wbf = (unsigned short*)(ws + OFF_WBF);
        merge_w_kernel<<<Z_N * OUT_D, 256, 0, stream>>>(weights, lora_A, lora_B, Wbf);
        apply_kernel<<<B_N, 256, 0, stream>>>(t, attrs, Wbf, out);
    } else {
        apply_fallback_kernel<<<B_N, 256, 0, stream>>>(t, attrs, weights, lora_A, lora_B, out);
    }
}